// Round 7
// baseline (294.039 us; speedup 1.0000x reference)
//
#include <hip/hip_runtime.h>
#include <math.h>

// Problem dims
#define BB 2048
#define CC 64
#define BERT 768
#define N_CTRY 250
#define N_CODES 654

// ws float offsets
#define OFF_PCHAT   0                          // [250][24] normalized country projections
#define OFF_CODEHAT (N_CTRY * 24)              // [654][8]  normalized code embeddings
#define OFF_XALL    (OFF_CODEHAT + N_CODES*8)  // [2048][80] raw projections (+bias)
#define OFF_SSQ     (OFF_XALL + BB*80)         // [2048][20] per-(row,jquad) sumsq partials
#define OFF_CTR     (OFF_SSQ + BB*20)          // barrier counter (memset to 0 pre-launch)

#define NBLK   512                             // all co-resident: LDS 25 KB -> >=4 blk/CU cap
#define NWAVES (NBLK * 4)                      // 2048 persistent waves
#define RPB    8
#define TPROJ  5120                            // 5 cb x 256 rowgrps x 4 jquads
#define TCTRY  (TPROJ + N_CTRY)                // 5370
#define NTASK  (TCTRY + 11)                    // 5381 (11 code chunks of 64)

// ---------------------------------------------------------------------------
// Single fused kernel: phase A (wave-task projection + precompute) ->
// device barrier -> phase B (classify + softmax).
// ---------------------------------------------------------------------------
__global__ __launch_bounds__(256) void k_all(
    const float* __restrict__ place, const float* __restrict__ other,
    const float* __restrict__ doc,
    const float* __restrict__ W_t2c, const float* __restrict__ b_t2c,
    const float* __restrict__ W_code, const float* __restrict__ b_code,
    const float* __restrict__ W_ctx, const float* __restrict__ b_ctx,
    const float* __restrict__ ctab, const float* __restrict__ W_cet,
    const float* __restrict__ b_cet, const float* __restrict__ code_emb,
    const int* __restrict__ fcodes, const int* __restrict__ ccodes,
    const float* __restrict__ gaz,
    const float* __restrict__ W_mix1, const float* __restrict__ b_mix1,
    const float* __restrict__ W_mix2, const float* __restrict__ b_mix2,
    const float* __restrict__ W_last, const float* __restrict__ b_last,
    float* __restrict__ ws, float* __restrict__ out) {
  __shared__ float s_pch[N_CTRY * 25];         // 25 KB (classify phase)

  const int tid = threadIdx.x;
  const int w = tid >> 6, lane = tid & 63;
  const int kq = lane >> 2, jsub = lane & 3;
  const int gw = blockIdx.x * 4 + w;

  float* pchat   = ws + OFF_PCHAT;
  float* codehat = ws + OFF_CODEHAT;
  float* xall    = ws + OFF_XALL;
  float* ssq     = ws + OFF_SSQ;

  // ================= phase A: wave-granular task loop =================
  for (int t = gw; t < NTASK; t += NWAVES) {
    if (t < TPROJ) {
      // ---- projection task: (cb, rowgrp, jquad), 4 j's x 8 rows ----
      const int cb = t >> 10;                  // 0..4
      const int rem = t & 1023;
      const int row0 = (rem >> 2) * RPB;
      const int jquad = rem & 3;
      const int j0 = cb * 16 + jquad * 4;      // wave-uniform
      const float* wbase; const float* xbase; const float* bbase; int jb;
      if (j0 < 24)      { wbase = W_t2c;  bbase = b_t2c;  jb = j0;      xbase = place; }
      else if (j0 < 32) { wbase = W_code; bbase = b_code; jb = j0 - 24; xbase = place; }
      else if (j0 < 56) { wbase = W_ctx;  bbase = b_ctx;  jb = j0 - 32; xbase = other; }
      else              { wbase = W_ctx;  bbase = b_ctx;  jb = j0 - 56; xbase = doc;   }
      const float bias = bbase[jb + jsub];

      float4 wv[12];
      {
        const float4* wr = (const float4*)(wbase + (size_t)(jb + jsub) * BERT);
#pragma unroll
        for (int i = 0; i < 12; ++i) wv[i] = wr[kq + 16 * i];
      }
      float acc[RPB];
#pragma unroll
      for (int r = 0; r < RPB; ++r) {
        const float4* xr = (const float4*)(xbase + (size_t)(row0 + r) * BERT);
        float s0 = 0.f, s1 = 0.f, s2 = 0.f, s3 = 0.f;
#pragma unroll
        for (int i = 0; i < 12; i += 4) {
          float4 a0 = xr[kq + 16 * (i + 0)];
          float4 a1 = xr[kq + 16 * (i + 1)];
          float4 a2 = xr[kq + 16 * (i + 2)];
          float4 a3 = xr[kq + 16 * (i + 3)];
          s0 += a0.x*wv[i+0].x + a0.y*wv[i+0].y + a0.z*wv[i+0].z + a0.w*wv[i+0].w;
          s1 += a1.x*wv[i+1].x + a1.y*wv[i+1].y + a1.z*wv[i+1].z + a1.w*wv[i+1].w;
          s2 += a2.x*wv[i+2].x + a2.y*wv[i+2].y + a2.z*wv[i+2].z + a2.w*wv[i+2].w;
          s3 += a3.x*wv[i+3].x + a3.y*wv[i+3].y + a3.z*wv[i+3].z + a3.w*wv[i+3].w;
        }
        acc[r] = (s0 + s1) + (s2 + s3);
      }
      // batched butterfly over kq bits (8 independent chains)
#pragma unroll
      for (int m = 4; m <= 32; m <<= 1)
#pragma unroll
        for (int r = 0; r < RPB; ++r) acc[r] += __shfl_xor(acc[r], m, 64);

      float v2[RPB];
#pragma unroll
      for (int r = 0; r < RPB; ++r) {
        acc[r] += bias;
        v2[r] = acc[r] * acc[r];
      }
      if (kq == 0) {
#pragma unroll
        for (int r = 0; r < RPB; ++r)
          xall[(size_t)(row0 + r) * 80 + j0 + jsub] = acc[r];
      }
#pragma unroll
      for (int r = 0; r < RPB; ++r) v2[r] += __shfl_xor(v2[r], 1, 64);
#pragma unroll
      for (int r = 0; r < RPB; ++r) v2[r] += __shfl_xor(v2[r], 2, 64);
      if (lane == 0) {
#pragma unroll
        for (int r = 0; r < RPB; ++r)
          ssq[(size_t)(row0 + r) * 20 + cb * 4 + jquad] = v2[r];
      }
    } else if (t < TCTRY) {
      // ---- country task: one wave -> 24 normalized outputs ----
      const int b = t - TPROJ;
      const float4* xr = (const float4*)(ctab + (size_t)b * BERT);
      float4 xa[12];
#pragma unroll
      for (int i = 0; i < 12; ++i) xa[i] = xr[kq + 16 * i];
      float val[6];
#pragma unroll
      for (int g = 0; g < 6; ++g) {
        const int j = 4 * g + jsub;
        const float4* wr = (const float4*)(W_cet + (size_t)j * BERT);
        float s0 = 0.f, s1 = 0.f, s2 = 0.f, s3 = 0.f;
#pragma unroll
        for (int i = 0; i < 12; i += 4) {
          float4 w0 = wr[kq + 16 * (i + 0)];
          float4 w1 = wr[kq + 16 * (i + 1)];
          float4 w2 = wr[kq + 16 * (i + 2)];
          float4 w3 = wr[kq + 16 * (i + 3)];
          s0 += xa[i+0].x*w0.x + xa[i+0].y*w0.y + xa[i+0].z*w0.z + xa[i+0].w*w0.w;
          s1 += xa[i+1].x*w1.x + xa[i+1].y*w1.y + xa[i+1].z*w1.z + xa[i+1].w*w1.w;
          s2 += xa[i+2].x*w2.x + xa[i+2].y*w2.y + xa[i+2].z*w2.z + xa[i+2].w*w2.w;
          s3 += xa[i+3].x*w3.x + xa[i+3].y*w3.y + xa[i+3].z*w3.z + xa[i+3].w*w3.w;
        }
        val[g] = (s0 + s1) + (s2 + s3);
      }
#pragma unroll
      for (int m = 4; m <= 32; m <<= 1)
#pragma unroll
        for (int g = 0; g < 6; ++g) val[g] += __shfl_xor(val[g], m, 64);
      float ss = 0.f;
#pragma unroll
      for (int g = 0; g < 6; ++g) {
        val[g] += b_cet[4 * g + jsub];
        ss += val[g] * val[g];
      }
      ss += __shfl_xor(ss, 1, 64);
      ss += __shfl_xor(ss, 2, 64);
      const float inv = 1.f / fmaxf(sqrtf(ss), 1e-8f);
      if (kq == 0) {
#pragma unroll
        for (int g = 0; g < 6; ++g) pchat[b * 24 + 4 * g + jsub] = val[g] * inv;
      }
    } else {
      // ---- code-norm task: 64 rows per wave ----
      const int idx = (t - TCTRY) * 64 + lane;
      if (idx < N_CODES) {
        float v[8];
        float ss = 0.f;
#pragma unroll
        for (int k = 0; k < 8; ++k) { v[k] = code_emb[idx * 8 + k]; ss += v[k] * v[k]; }
        const float inv = 1.f / fmaxf(sqrtf(ss), 1e-8f);
#pragma unroll
        for (int k = 0; k < 8; ++k) codehat[idx * 8 + k] = v[k] * inv;
      }
    }
  }

  // ================= device-wide barrier =================
  __threadfence();                     // flush this thread's writes (agent scope)
  __syncthreads();
  if (tid == 0) {
    unsigned* ctr = (unsigned*)(ws + OFF_CTR);
    atomicAdd(ctr, 1u);                // device-scope by default on CDNA
    while (__hip_atomic_load(ctr, __ATOMIC_ACQUIRE, __HIP_MEMORY_SCOPE_AGENT) < NBLK)
      __builtin_amdgcn_s_sleep(2);
  }
  __syncthreads();
  __threadfence();                     // invalidate stale cached lines

  // ================= phase B: classify (wave w -> row bid*4+w) =================
  for (int e = tid; e < N_CTRY * 24; e += 256)
    s_pch[(e / 24) * 25 + (e % 24)] = pchat[e];
  __syncthreads();

  const int row = __builtin_amdgcn_readfirstlane(blockIdx.x * 4 + w);
  const float* xv = xall + (size_t)row * 80;   // wave-uniform -> s_load
  const float* q  = ssq  + (size_t)row * 20;   // wave-uniform -> s_load
  const float g0 = q[0]+q[1]+q[2]+q[3]+q[4]+q[5];
  const float g1 = q[6]+q[7];
  const float g2 = q[8]+q[9]+q[10]+q[11]+q[12]+q[13];
  const float g3 = q[14]+q[15]+q[16]+q[17]+q[18]+q[19];
  const float inv0 = 1.f / fmaxf(sqrtf(g0), 1e-8f);
  const float inv1 = 1.f / fmaxf(sqrtf(g1), 1e-8f);
  const float inv2 = 1.f / fmaxf(sqrtf(g2), 1e-8f);
  const float inv3 = 1.f / fmaxf(sqrtf(g3), 1e-8f);

  const int cidx = ccodes[row * CC + lane];
  const int fidx = fcodes[row * CC + lane];

  float cc[24];
#pragma unroll
  for (int k = 0; k < 24; ++k) cc[k] = s_pch[cidx * 25 + k];
  float cd[8];
  {
    const float4* q4 = (const float4*)(codehat + fidx * 8);
#pragma unroll
    for (int i = 0; i < 2; ++i) {
      float4 v = q4[i];
      cd[4*i+0] = v.x; cd[4*i+1] = v.y; cd[4*i+2] = v.z; cd[4*i+3] = v.w;
    }
  }

  float sc = 0.f, so = 0.f, sd = 0.f, sq = 0.f;
#pragma unroll
  for (int k = 0; k < 24; ++k) {
    const float ck = cc[k];
    sc += xv[k] * ck;
    so += xv[32 + k] * ck;
    sd += xv[56 + k] * ck;
  }
#pragma unroll
  for (int k = 0; k < 8; ++k) sq += xv[24 + k] * cd[k];

  float f[13];
  f[0] = sc * inv0;
  f[1] = sq * inv1;
  f[2] = so * inv2;
  f[3] = sd * inv3;
  {
    const float* g = gaz + (size_t)(row * CC + lane) * 9;
    float4 ga = ((const float4*)g)[0];
    float4 gb = ((const float4*)g)[1];
    f[4] = ga.x; f[5] = ga.y; f[6] = ga.z; f[7] = ga.w;
    f[8] = gb.x; f[9] = gb.y; f[10] = gb.z; f[11] = gb.w;
    f[12] = g[8];
  }

  float h1[24];
#pragma unroll
  for (int j = 0; j < 24; ++j) {
    float a = b_mix1[j];
#pragma unroll
    for (int i = 0; i < 13; ++i) a += W_mix1[j * 13 + i] * f[i];
    h1[j] = 1.f / (1.f + __expf(-a));
  }
  float h2[24];
#pragma unroll
  for (int j = 0; j < 24; ++j) {
    float a = b_mix2[j];
#pragma unroll
    for (int i = 0; i < 24; ++i) a += W_mix2[j * 24 + i] * h1[i];
    h2[j] = 1.f / (1.f + __expf(-a));
  }
  float last = b_last[0];
#pragma unroll
  for (int k = 0; k < 24; ++k) last += W_last[k] * h2[k];

  float mx = last;
#pragma unroll
  for (int s = 32; s >= 1; s >>= 1) mx = fmaxf(mx, __shfl_xor(mx, s, 64));
  const float e = __expf(last - mx);
  float ssum = e;
#pragma unroll
  for (int s = 32; s >= 1; s >>= 1) ssum += __shfl_xor(ssum, s, 64);
  out[row * CC + lane] = e / ssum;
}

// ---------------------------------------------------------------------------
extern "C" void kernel_launch(void* const* d_in, const int* in_sizes, int n_in,
                              void* d_out, int out_size, void* d_ws, size_t ws_size,
                              hipStream_t stream) {
  const float* place   = (const float*)d_in[0];
  const float* other   = (const float*)d_in[1];
  const float* doc     = (const float*)d_in[2];
  const int*   fcodes  = (const int*)d_in[3];
  const int*   ccodes  = (const int*)d_in[4];
  const float* gaz     = (const float*)d_in[5];
  const float* code_emb= (const float*)d_in[6];
  const float* ctab    = (const float*)d_in[7];
  const float* W_cet   = (const float*)d_in[8];
  const float* b_cet   = (const float*)d_in[9];
  const float* W_t2c   = (const float*)d_in[10];
  const float* b_t2c   = (const float*)d_in[11];
  const float* W_ctx   = (const float*)d_in[12];
  const float* b_ctx   = (const float*)d_in[13];
  const float* W_code  = (const float*)d_in[14];
  const float* b_code  = (const float*)d_in[15];
  const float* W_mix1  = (const float*)d_in[16];
  const float* b_mix1  = (const float*)d_in[17];
  const float* W_mix2  = (const float*)d_in[18];
  const float* b_mix2  = (const float*)d_in[19];
  const float* W_last  = (const float*)d_in[20];
  const float* b_last  = (const float*)d_in[21];
  float* ws  = (float*)d_ws;
  float* out = (float*)d_out;

  // zero the barrier counter (stream-ordered; graph-capturable memset node)
  hipMemsetAsync((char*)d_ws + (size_t)OFF_CTR * sizeof(float), 0, sizeof(unsigned), stream);
  k_all<<<NBLK, 256, 0, stream>>>(
      place, other, doc, W_t2c, b_t2c, W_code, b_code, W_ctx, b_ctx,
      ctab, W_cet, b_cet, code_emb, fcodes, ccodes, gaz,
      W_mix1, b_mix1, W_mix2, b_mix2, W_last, b_last, ws, out);
}